// Round 1
// baseline (583.860 us; speedup 1.0000x reference)
//
#include <hip/hip_runtime.h>
#include <hip/hip_bf16.h>
#include <math.h>

// Problem constants
constexpr int Ncfg = 4096;
constexpr int Dcfg = 4096;
constexpr int Ocfg = 4096;
constexpr int Ecfg = 8;
constexpr int Rcfg = 16;
constexpr int KD   = Dcfg + Ecfg * Rcfg;   // 4224 fused-K
constexpr float ALPHA_C = 1.0f;
constexpr double TEMP_C = 1.0;

// Workspace layout (bytes)
constexpr size_t BT_OFF = 0;                                   // B'^T bf16 [O][KD]
constexpr size_t AP_OFF = BT_OFF + (size_t)Ocfg * KD * 2;      // A'   bf16 [N][KD]
constexpr size_t AT_OFF = AP_OFF + (size_t)Ncfg * KD * 2;      // lora_A^T bf16 [E][R][D]
constexpr size_t G_OFF  = AT_OFF + (size_t)Ecfg * Rcfg * Dcfg * 2; // gates f32 [N][16]
// total ~70.5 MB

typedef short bf16x8 __attribute__((ext_vector_type(8)));
typedef float f32x4  __attribute__((ext_vector_type(4)));

__device__ __forceinline__ void async_load16(const __hip_bfloat16* g, __hip_bfloat16* l) {
  __builtin_amdgcn_global_load_lds((__attribute__((address_space(1))) void*)(g),
                                   (__attribute__((address_space(3))) void*)(l), 16, 0, 0);
}

// ---------------------------------------------------------------------------
// K1: generic 64x64 tiled transpose + fp32->bf16 cast.
// dst[(c)*dstPitch + dstOff + r] = src[r*srcPitch + c]
// ---------------------------------------------------------------------------
__global__ void transpose_cast_kernel(const float* __restrict__ src,
                                      __hip_bfloat16* __restrict__ dst,
                                      int srcPitch, int dstPitch, int dstOff) {
  __shared__ float tile[64][65];   // +1 pad: conflict-free on both phases
  const int r0 = blockIdx.x * 64;  // src row
  const int c0 = blockIdx.y * 64;  // src col
  const int tid = threadIdx.x;
#pragma unroll
  for (int it = 0; it < 16; it++) {
    int idx = it * 256 + tid;
    int i = idx >> 6, j = idx & 63;
    tile[i][j] = src[(size_t)(r0 + i) * srcPitch + (c0 + j)];
  }
  __syncthreads();
#pragma unroll
  for (int it = 0; it < 16; it++) {
    int idx = it * 256 + tid;
    int j = idx >> 6, i = idx & 63;
    dst[(size_t)(c0 + j) * dstPitch + dstOff + (r0 + i)] = __float2bfloat16(tile[i][j]);
  }
}

// ---------------------------------------------------------------------------
// K1c: lora_A (E,D,R) fp32 -> AT (E,R,D) bf16
// ---------------------------------------------------------------------------
__global__ void loraA_transpose_kernel(const float* __restrict__ A,
                                       __hip_bfloat16* __restrict__ AT) {
  const int e  = blockIdx.y;
  const int d0 = blockIdx.x * 256;
  const int tid = threadIdx.x;
  __shared__ float tile[256][17];
#pragma unroll
  for (int it = 0; it < 16; it++) {
    int idx = it * 256 + tid;            // flat over 256 d x 16 r
    int d = idx >> 4, rr = idx & 15;
    tile[d][rr] = A[((size_t)e * Dcfg + d0 + d) * Rcfg + rr];
  }
  __syncthreads();
#pragma unroll
  for (int rr = 0; rr < Rcfg; rr++) {
    AT[((size_t)e * Rcfg + rr) * Dcfg + d0 + tid] = __float2bfloat16(tile[tid][rr]);
  }
}

// ---------------------------------------------------------------------------
// K2: gate logits (fp64 accumulation -> exact-enough top-2) + sparse softmax.
// gates[n*16 + e], e in [0,9)
// ---------------------------------------------------------------------------
__global__ void gates_kernel(const float* __restrict__ x,
                             const float* __restrict__ gw,
                             float* __restrict__ gates) {
  __shared__ double red[9][257];
  const int n = blockIdx.x, tid = threadIdx.x;
  const float* xr = x + (size_t)n * Dcfg;
  double acc[9];
#pragma unroll
  for (int e = 0; e < 9; e++) acc[e] = 0.0;
  for (int d = tid; d < Dcfg; d += 256) {
    double xv = (double)xr[d];
#pragma unroll
    for (int e = 0; e < 9; e++) acc[e] += xv * (double)gw[e * Dcfg + d];
  }
#pragma unroll
  for (int e = 0; e < 9; e++) red[e][tid] = acc[e];
  __syncthreads();
  for (int s = 128; s > 0; s >>= 1) {
    if (tid < s) {
#pragma unroll
      for (int e = 0; e < 9; e++) red[e][tid] += red[e][tid + s];
    }
    __syncthreads();
  }
  if (tid == 0) {
    double lg[9];
#pragma unroll
    for (int e = 0; e < 9; e++) lg[e] = red[e][0];
    // top-2 over experts 1..8, lowest index wins ties (jax top_k semantics)
    int i1 = 1;
    for (int e = 2; e <= 8; e++) if (lg[e] > lg[i1]) i1 = e;
    int i2 = -1; double v2 = -1e300;
    for (int e = 1; e <= 8; e++) if (e != i1 && lg[e] > v2) { v2 = lg[e]; i2 = e; }
    double vals[9];
    vals[0] = lg[0];
    for (int e = 1; e <= 8; e++) vals[e] = (e == i1 || e == i2) ? lg[e] : 0.0; // zeros, NOT -inf
    double mx = vals[0];
    for (int e = 1; e < 9; e++) mx = fmax(mx, vals[e]);
    double se = 0.0, ex[9];
    for (int e = 0; e < 9; e++) { ex[e] = exp((vals[e] - mx) / TEMP_C); se += ex[e]; }
    for (int e = 0; e < 9; e++) gates[n * 16 + e] = (float)(ex[e] / se);
  }
}

// ---------------------------------------------------------------------------
// K3: A'[n, 0:D] = bf16(g0[n] * x[n, :])
// ---------------------------------------------------------------------------
__global__ void scale_x_kernel(const float* __restrict__ x,
                               const float* __restrict__ gates,
                               __hip_bfloat16* __restrict__ Ap) {
  const int n = blockIdx.x;
  const float g0 = gates[n * 16];
  const float4* xr = (const float4*)(x + (size_t)n * Dcfg);
  __hip_bfloat16* ar = Ap + (size_t)n * KD;
  const int tid = threadIdx.x;
#pragma unroll
  for (int it = 0; it < 4; it++) {
    int c = it * 256 + tid;              // float4 index, 0..1023
    float4 v = xr[c];
    union { ushort4 u; __hip_bfloat16 h[4]; } p;
    p.h[0] = __float2bfloat16(g0 * v.x);
    p.h[1] = __float2bfloat16(g0 * v.y);
    p.h[2] = __float2bfloat16(g0 * v.z);
    p.h[3] = __float2bfloat16(g0 * v.w);
    *(ushort4*)(ar + (size_t)c * 4) = p.u;
  }
}

// ---------------------------------------------------------------------------
// K4: t[n,e,:] = x[n,:] @ lora_A[e]  via 16x16x32 bf16 MFMA, one wave per
// 16-row tile handling all 8 experts; epilogue writes
// A'[n, 4096 + e*16 + r] = bf16(ALPHA * g_{1+e}[n] * t[n,e,r])
// C/D layout: col(r) = lane&15, row = (lane>>4)*4 + reg   [m89-verified]
// ---------------------------------------------------------------------------
__global__ void lora_t_kernel(const float* __restrict__ x,
                              const __hip_bfloat16* __restrict__ AT,
                              const float* __restrict__ gates,
                              __hip_bfloat16* __restrict__ Ap) {
  const int n0 = blockIdx.x * 16;
  const int lane = threadIdx.x & 63;
  const int m = lane & 15, quad = lane >> 4;
  f32x4 acc[8] = {};
  const float* xrow = x + (size_t)(n0 + m) * Dcfg + quad * 8;
  const __hip_bfloat16* atb = AT + (size_t)m * Dcfg + quad * 8;
#pragma unroll 2
  for (int kb = 0; kb < Dcfg; kb += 32) {
    float4 x0 = *(const float4*)(xrow + kb);
    float4 x1 = *(const float4*)(xrow + kb + 4);
    union { bf16x8 v; __hip_bfloat16 h[8]; } a;
    a.h[0] = __float2bfloat16(x0.x); a.h[1] = __float2bfloat16(x0.y);
    a.h[2] = __float2bfloat16(x0.z); a.h[3] = __float2bfloat16(x0.w);
    a.h[4] = __float2bfloat16(x1.x); a.h[5] = __float2bfloat16(x1.y);
    a.h[6] = __float2bfloat16(x1.z); a.h[7] = __float2bfloat16(x1.w);
#pragma unroll
    for (int e = 0; e < Ecfg; e++) {
      bf16x8 b = *(const bf16x8*)(atb + (size_t)e * Rcfg * Dcfg + kb);
      acc[e] = __builtin_amdgcn_mfma_f32_16x16x32_bf16(a.v, b, acc[e], 0, 0, 0);
    }
  }
#pragma unroll
  for (int e = 0; e < Ecfg; e++) {
#pragma unroll
    for (int rg = 0; rg < 4; rg++) {
      int n = n0 + quad * 4 + rg;
      float g = gates[n * 16 + 1 + e];
      Ap[(size_t)n * KD + Dcfg + e * Rcfg + m] =
          __float2bfloat16(ALPHA_C * g * acc[e][rg]);
    }
  }
}

// ---------------------------------------------------------------------------
// K5: fused GEMM  out = A'(N x KD) @ B'(KD x O) + g0[n]*bias[o]
// m97 structure: 128x128 tile, BK=32, 4 waves, 4x4 16x16x32 MFMA per wave,
// global_load_lds width-16 staging (LDS dest = wave-uniform base + lane*16,
// so LDS tile layout is exactly [row][k] contiguous, no padding).
// ---------------------------------------------------------------------------
__global__ __launch_bounds__(256) void gemm_kernel(
    const __hip_bfloat16* __restrict__ Ap, const __hip_bfloat16* __restrict__ BT,
    const float* __restrict__ gates, const float* __restrict__ bias,
    float* __restrict__ out) {
  __shared__ __hip_bfloat16 As[128 * 32];
  __shared__ __hip_bfloat16 Bs[128 * 32];
  const int tid = threadIdx.x;
  const int m0 = blockIdx.y * 128, n0 = blockIdx.x * 128;
  const int wave = tid >> 6, lane = tid & 63;
  const int wm = (wave & 1) * 64, wn = (wave >> 1) * 64;
  const int mr = lane & 15, quad = lane >> 4;

  f32x4 acc[4][4] = {};

  // staging: thread t loads 16B = 8 bf16 at (row = t>>2, kcol = (t&3)*8)
  const int srow = tid >> 2;
  const int kc = (tid & 3) * 8;
  const __hip_bfloat16* gA0 = Ap + (size_t)(m0 + srow) * KD + kc;
  const __hip_bfloat16* gA1 = gA0 + (size_t)64 * KD;
  const __hip_bfloat16* gB0 = BT + (size_t)(n0 + srow) * KD + kc;
  const __hip_bfloat16* gB1 = gB0 + (size_t)64 * KD;
  __hip_bfloat16* lA0 = As + tid * 8;          // == (t>>2)*32 + (t&3)*8
  __hip_bfloat16* lA1 = As + 64 * 32 + tid * 8;
  __hip_bfloat16* lB0 = Bs + tid * 8;
  __hip_bfloat16* lB1 = Bs + 64 * 32 + tid * 8;

  for (int kb = 0; kb < KD; kb += 32) {
    __syncthreads();   // previous iter's LDS reads done before overwrite
    async_load16(gA0 + kb, lA0);
    async_load16(gA1 + kb, lA1);
    async_load16(gB0 + kb, lB0);
    async_load16(gB1 + kb, lB1);
    asm volatile("s_waitcnt vmcnt(0)" ::: "memory");
    __syncthreads();

    bf16x8 a[4], b[4];
#pragma unroll
    for (int i = 0; i < 4; i++)
      a[i] = *(const bf16x8*)&As[(wm + i * 16 + mr) * 32 + quad * 8];
#pragma unroll
    for (int j = 0; j < 4; j++)
      b[j] = *(const bf16x8*)&Bs[(wn + j * 16 + mr) * 32 + quad * 8];
#pragma unroll
    for (int i = 0; i < 4; i++)
#pragma unroll
      for (int j = 0; j < 4; j++)
        acc[i][j] = __builtin_amdgcn_mfma_f32_16x16x32_bf16(a[i], b[j], acc[i][j], 0, 0, 0);
  }

  // epilogue: C/D layout col = lane&15, row = quad*4 + reg
#pragma unroll
  for (int i = 0; i < 4; i++) {
    const int rowb = m0 + wm + i * 16 + quad * 4;
#pragma unroll
    for (int rg = 0; rg < 4; rg++) {
      const int row = rowb + rg;
      const float g0 = gates[row * 16];
#pragma unroll
      for (int j = 0; j < 4; j++) {
        const int col = n0 + wn + j * 16 + mr;
        out[(size_t)row * Ocfg + col] = acc[i][j][rg] + g0 * bias[col];
      }
    }
  }
}

// ---------------------------------------------------------------------------
extern "C" void kernel_launch(void* const* d_in, const int* in_sizes, int n_in,
                              void* d_out, int out_size, void* d_ws, size_t ws_size,
                              hipStream_t stream) {
  const float* x  = (const float*)d_in[0];
  const float* W  = (const float*)d_in[1];   // (D, O)
  const float* b  = (const float*)d_in[2];   // (O,)
  const float* lA = (const float*)d_in[3];   // (E, D, R)
  const float* lB = (const float*)d_in[4];   // (E, R, O)
  const float* gw = (const float*)d_in[5];   // (E+1, D)
  // d_in[6] = bvv, unused by the reference
  float* out = (float*)d_out;

  char* ws = (char*)d_ws;
  __hip_bfloat16* BT    = (__hip_bfloat16*)(ws + BT_OFF);
  __hip_bfloat16* Ap    = (__hip_bfloat16*)(ws + AP_OFF);
  __hip_bfloat16* AT    = (__hip_bfloat16*)(ws + AT_OFF);
  float*          gates = (float*)(ws + G_OFF);

  // B'^T rows: [o][0:4096] = W^T, [o][4096+e*16+r] = lora_B[e][r][o]
  transpose_cast_kernel<<<dim3(64, 64), 256, 0, stream>>>(W, BT, Ocfg, KD, 0);
  transpose_cast_kernel<<<dim3(2, 64), 256, 0, stream>>>(lB, BT, Ocfg, KD, Dcfg);
  loraA_transpose_kernel<<<dim3(16, 8), 256, 0, stream>>>(lA, AT);
  gates_kernel<<<dim3(Ncfg), 256, 0, stream>>>(x, gw, gates);
  scale_x_kernel<<<dim3(Ncfg), 256, 0, stream>>>(x, gates, Ap);
  lora_t_kernel<<<dim3(Ncfg / 16), 64, 0, stream>>>(x, AT, gates, Ap);
  gemm_kernel<<<dim3(Ocfg / 128, Ncfg / 128), 256, 0, stream>>>(Ap, BT, gates, b, out);
}

// Round 2
// 434.078 us; speedup vs baseline: 1.3451x; 1.3451x over previous
//
#include <hip/hip_runtime.h>
#include <hip/hip_bf16.h>
#include <math.h>

// Problem constants
constexpr int Ncfg = 4096;
constexpr int Dcfg = 4096;
constexpr int Ocfg = 4096;
constexpr int Ecfg = 8;
constexpr int Rcfg = 16;
constexpr int KD   = Dcfg + Ecfg * Rcfg;   // 4224 fused-K
constexpr float ALPHA_C = 1.0f;
constexpr double TEMP_C = 1.0;

// Workspace layout (bytes)
constexpr size_t BT_OFF = 0;                                   // B'^T bf16 [O][KD]
constexpr size_t AP_OFF = BT_OFF + (size_t)Ocfg * KD * 2;      // A'   bf16 [N][KD]
constexpr size_t AT_OFF = AP_OFF + (size_t)Ncfg * KD * 2;      // lora_A^T bf16 [E][R][D]
constexpr size_t G_OFF  = AT_OFF + (size_t)Ecfg * Rcfg * Dcfg * 2; // gates f32 [N][16]
// total ~70.5 MB

typedef short bf16x8 __attribute__((ext_vector_type(8)));
typedef float f32x4  __attribute__((ext_vector_type(4)));

__device__ __forceinline__ void async_load16(const __hip_bfloat16* g, __hip_bfloat16* l) {
  __builtin_amdgcn_global_load_lds((__attribute__((address_space(1))) void*)(g),
                                   (__attribute__((address_space(3))) void*)(l), 16, 0, 0);
}

// ---------------------------------------------------------------------------
// K1: 64x64 tiled transpose + fp32->bf16 cast, vectorized both phases.
// dst[c*dstPitch + dstOff + r] = src[r*srcPitch + c]
// Phase1: float4 global loads, scalar LDS writes (2-way bank alias = free).
// Phase2: 4x strided LDS reads (stride 65 -> bank step 4, 2-way = free),
//         ushort4 packed bf16 stores (8B/lane).
// ---------------------------------------------------------------------------
__global__ void transpose_cast_kernel(const float* __restrict__ src,
                                      __hip_bfloat16* __restrict__ dst,
                                      int srcPitch, int dstPitch, int dstOff) {
  __shared__ float tile[64][65];
  const int r0 = blockIdx.x * 64;  // src row
  const int c0 = blockIdx.y * 64;  // src col
  const int tid = threadIdx.x;
#pragma unroll
  for (int it = 0; it < 4; it++) {
    int flat = it * 256 + tid;          // [0,1024)
    int i = flat >> 4, f = flat & 15;   // row i, float4 f
    float4 v = *(const float4*)(src + (size_t)(r0 + i) * srcPitch + c0 + 4 * f);
    tile[i][4 * f + 0] = v.x;
    tile[i][4 * f + 1] = v.y;
    tile[i][4 * f + 2] = v.z;
    tile[i][4 * f + 3] = v.w;
  }
  __syncthreads();
#pragma unroll
  for (int it = 0; it < 4; it++) {
    int flat = it * 256 + tid;
    int j = flat >> 4, q = flat & 15;   // dst row j, ushort4 q
    union { ushort4 u; __hip_bfloat16 h[4]; } p;
    p.h[0] = __float2bfloat16(tile[4 * q + 0][j]);
    p.h[1] = __float2bfloat16(tile[4 * q + 1][j]);
    p.h[2] = __float2bfloat16(tile[4 * q + 2][j]);
    p.h[3] = __float2bfloat16(tile[4 * q + 3][j]);
    *(ushort4*)(dst + (size_t)(c0 + j) * dstPitch + dstOff + r0 + 4 * q) = p.u;
  }
}

// ---------------------------------------------------------------------------
// K1c: lora_A (E,D,R) fp32 -> AT (E,R,D) bf16
// ---------------------------------------------------------------------------
__global__ void loraA_transpose_kernel(const float* __restrict__ A,
                                       __hip_bfloat16* __restrict__ AT) {
  const int e  = blockIdx.y;
  const int d0 = blockIdx.x * 256;
  const int tid = threadIdx.x;
  __shared__ float tile[256][17];
#pragma unroll
  for (int it = 0; it < 16; it++) {
    int idx = it * 256 + tid;            // flat over 256 d x 16 r
    int d = idx >> 4, rr = idx & 15;
    tile[d][rr] = A[((size_t)e * Dcfg + d0 + d) * Rcfg + rr];
  }
  __syncthreads();
#pragma unroll
  for (int rr = 0; rr < Rcfg; rr++) {
    AT[((size_t)e * Rcfg + rr) * Dcfg + d0 + tid] = __float2bfloat16(tile[tid][rr]);
  }
}

// ---------------------------------------------------------------------------
// K2: fused gates + base-scale. One block per row n.
// Thread t caches its 16 x-values (4 float4) in registers, accumulates the 9
// gate logits in fp64 (top-2 is a discrete decision; keep it exact), wave
// shuffle-reduce + LDS combine, thread 0 does top-2 + sparse softmax (zeros,
// NOT -inf, for non-top-k), then all threads write A'[n,0:D] = bf16(g0*x)
// straight from registers — no second x read.
// ---------------------------------------------------------------------------
__global__ __launch_bounds__(256) void gates_scale_kernel(
    const float* __restrict__ x, const float* __restrict__ gw,
    float* __restrict__ gates, __hip_bfloat16* __restrict__ Ap) {
  const int n = blockIdx.x, tid = threadIdx.x;
  const int wave = tid >> 6, lane = tid & 63;
  const float4* xr = (const float4*)(x + (size_t)n * Dcfg);
  const float4* gw4 = (const float4*)gw;

  float4 xv[4];
  double acc[9];
#pragma unroll
  for (int e = 0; e < 9; e++) acc[e] = 0.0;
#pragma unroll
  for (int it = 0; it < 4; it++) {
    int fi = it * 256 + tid;             // float4 index in row
    xv[it] = xr[fi];
#pragma unroll
    for (int e = 0; e < 9; e++) {
      float4 w = gw4[e * 1024 + fi];
      acc[e] += (double)xv[it].x * (double)w.x + (double)xv[it].y * (double)w.y +
                (double)xv[it].z * (double)w.z + (double)xv[it].w * (double)w.w;
    }
  }
  // wave reduce (64 lanes)
#pragma unroll
  for (int off = 32; off >= 1; off >>= 1) {
#pragma unroll
    for (int e = 0; e < 9; e++) acc[e] += __shfl_xor(acc[e], off, 64);
  }
  __shared__ double lred[4][9];
  __shared__ float gsh[16];
  if (lane == 0) {
#pragma unroll
    for (int e = 0; e < 9; e++) lred[wave][e] = acc[e];
  }
  __syncthreads();
  if (tid == 0) {
    double lg[9];
#pragma unroll
    for (int e = 0; e < 9; e++) lg[e] = lred[0][e] + lred[1][e] + lred[2][e] + lred[3][e];
    // top-2 over experts 1..8, lowest index wins ties (jax top_k semantics)
    int i1 = 1;
    for (int e = 2; e <= 8; e++) if (lg[e] > lg[i1]) i1 = e;
    int i2 = -1; double v2 = -1e300;
    for (int e = 1; e <= 8; e++) if (e != i1 && lg[e] > v2) { v2 = lg[e]; i2 = e; }
    double vals[9];
    vals[0] = lg[0];
    for (int e = 1; e <= 8; e++) vals[e] = (e == i1 || e == i2) ? lg[e] : 0.0;
    double mx = vals[0];
    for (int e = 1; e < 9; e++) mx = fmax(mx, vals[e]);
    double se = 0.0, ex[9];
    for (int e = 0; e < 9; e++) { ex[e] = exp((vals[e] - mx) / TEMP_C); se += ex[e]; }
    for (int e = 0; e < 9; e++) {
      float g = (float)(ex[e] / se);
      gates[n * 16 + e] = g;
      gsh[e] = g;
    }
  }
  __syncthreads();
  const float g0 = gsh[0];
  __hip_bfloat16* ar = Ap + (size_t)n * KD;
#pragma unroll
  for (int it = 0; it < 4; it++) {
    int fi = it * 256 + tid;
    union { ushort4 u; __hip_bfloat16 h[4]; } p;
    p.h[0] = __float2bfloat16(g0 * xv[it].x);
    p.h[1] = __float2bfloat16(g0 * xv[it].y);
    p.h[2] = __float2bfloat16(g0 * xv[it].z);
    p.h[3] = __float2bfloat16(g0 * xv[it].w);
    *(ushort4*)(ar + (size_t)fi * 4) = p.u;
  }
}

// ---------------------------------------------------------------------------
// K4: t[n,e,:] = x[n,:] @ lora_A[e] via 16x16x32 bf16 MFMA.
// v2: 4 waves/block, K split across waves (1024 each) -> 4x latency hiding
// vs round-1's 1 wave/CU. LDS reduce of the 8 f32x4 accumulators, then
// epilogue writes A'[n, 4096 + e*16 + r] = bf16(ALPHA * g_{1+e}[n] * t).
// C/D layout: col(r) = lane&15, row = (lane>>4)*4 + reg   [m89-verified]
// ---------------------------------------------------------------------------
__global__ __launch_bounds__(256) void lora_t_kernel(
    const float* __restrict__ x, const __hip_bfloat16* __restrict__ AT,
    const float* __restrict__ gates, __hip_bfloat16* __restrict__ Ap) {
  const int n0 = blockIdx.x * 16;
  const int tid = threadIdx.x;
  const int wave = tid >> 6, lane = tid & 63;
  const int m = lane & 15, quad = lane >> 4;
  const int kbase = wave * 1024;

  f32x4 acc[8] = {};
  const float* xrow = x + (size_t)(n0 + m) * Dcfg + kbase + quad * 8;
  const __hip_bfloat16* atb = AT + (size_t)m * Dcfg + kbase + quad * 8;
#pragma unroll 2
  for (int kb = 0; kb < 1024; kb += 32) {
    float4 x0 = *(const float4*)(xrow + kb);
    float4 x1 = *(const float4*)(xrow + kb + 4);
    union { bf16x8 v; __hip_bfloat16 h[8]; } a;
    a.h[0] = __float2bfloat16(x0.x); a.h[1] = __float2bfloat16(x0.y);
    a.h[2] = __float2bfloat16(x0.z); a.h[3] = __float2bfloat16(x0.w);
    a.h[4] = __float2bfloat16(x1.x); a.h[5] = __float2bfloat16(x1.y);
    a.h[6] = __float2bfloat16(x1.z); a.h[7] = __float2bfloat16(x1.w);
#pragma unroll
    for (int e = 0; e < Ecfg; e++) {
      bf16x8 b = *(const bf16x8*)(atb + (size_t)e * Rcfg * Dcfg + kb);
      acc[e] = __builtin_amdgcn_mfma_f32_16x16x32_bf16(a.v, b, acc[e], 0, 0, 0);
    }
  }
  // cross-wave reduction: red[wave][e][lane]
  __shared__ f32x4 red[4][8][64];
#pragma unroll
  for (int e = 0; e < Ecfg; e++) red[wave][e][lane] = acc[e];
  __syncthreads();
  // wave w handles experts 2w, 2w+1
#pragma unroll
  for (int ei = 0; ei < 2; ei++) {
    const int e = wave * 2 + ei;
    f32x4 s = red[0][e][lane] + red[1][e][lane] + red[2][e][lane] + red[3][e][lane];
#pragma unroll
    for (int rg = 0; rg < 4; rg++) {
      int n = n0 + quad * 4 + rg;
      float g = gates[n * 16 + 1 + e];
      Ap[(size_t)n * KD + Dcfg + e * Rcfg + m] = __float2bfloat16(ALPHA_C * g * s[rg]);
    }
  }
}

// ---------------------------------------------------------------------------
// K5: fused GEMM  out = A'(N x KD) @ B'(KD x O) + g0[n]*bias[o]
// m97 structure: 128x128 tile, BK=32, 4 waves, 4x4 16x16x32 MFMA per wave,
// global_load_lds width-16 staging (LDS dest = wave-uniform base + lane*16,
// so LDS tile layout is exactly [row][k] contiguous, no padding).
// ---------------------------------------------------------------------------
__global__ __launch_bounds__(256) void gemm_kernel(
    const __hip_bfloat16* __restrict__ Ap, const __hip_bfloat16* __restrict__ BT,
    const float* __restrict__ gates, const float* __restrict__ bias,
    float* __restrict__ out) {
  __shared__ __hip_bfloat16 As[128 * 32];
  __shared__ __hip_bfloat16 Bs[128 * 32];
  const int tid = threadIdx.x;
  const int m0 = blockIdx.y * 128, n0 = blockIdx.x * 128;
  const int wave = tid >> 6, lane = tid & 63;
  const int wm = (wave & 1) * 64, wn = (wave >> 1) * 64;
  const int mr = lane & 15, quad = lane >> 4;

  f32x4 acc[4][4] = {};

  const int srow = tid >> 2;
  const int kc = (tid & 3) * 8;
  const __hip_bfloat16* gA0 = Ap + (size_t)(m0 + srow) * KD + kc;
  const __hip_bfloat16* gA1 = gA0 + (size_t)64 * KD;
  const __hip_bfloat16* gB0 = BT + (size_t)(n0 + srow) * KD + kc;
  const __hip_bfloat16* gB1 = gB0 + (size_t)64 * KD;
  __hip_bfloat16* lA0 = As + tid * 8;
  __hip_bfloat16* lA1 = As + 64 * 32 + tid * 8;
  __hip_bfloat16* lB0 = Bs + tid * 8;
  __hip_bfloat16* lB1 = Bs + 64 * 32 + tid * 8;

  for (int kb = 0; kb < KD; kb += 32) {
    __syncthreads();
    async_load16(gA0 + kb, lA0);
    async_load16(gA1 + kb, lA1);
    async_load16(gB0 + kb, lB0);
    async_load16(gB1 + kb, lB1);
    asm volatile("s_waitcnt vmcnt(0)" ::: "memory");
    __syncthreads();

    bf16x8 a[4], b[4];
#pragma unroll
    for (int i = 0; i < 4; i++)
      a[i] = *(const bf16x8*)&As[(wm + i * 16 + mr) * 32 + quad * 8];
#pragma unroll
    for (int j = 0; j < 4; j++)
      b[j] = *(const bf16x8*)&Bs[(wn + j * 16 + mr) * 32 + quad * 8];
#pragma unroll
    for (int i = 0; i < 4; i++)
#pragma unroll
      for (int j = 0; j < 4; j++)
        acc[i][j] = __builtin_amdgcn_mfma_f32_16x16x32_bf16(a[i], b[j], acc[i][j], 0, 0, 0);
  }

#pragma unroll
  for (int i = 0; i < 4; i++) {
    const int rowb = m0 + wm + i * 16 + quad * 4;
#pragma unroll
    for (int rg = 0; rg < 4; rg++) {
      const int row = rowb + rg;
      const float g0 = gates[row * 16];
#pragma unroll
      for (int j = 0; j < 4; j++) {
        const int col = n0 + wn + j * 16 + mr;
        out[(size_t)row * Ocfg + col] = acc[i][j][rg] + g0 * bias[col];
      }
    }
  }
}

// ---------------------------------------------------------------------------
extern "C" void kernel_launch(void* const* d_in, const int* in_sizes, int n_in,
                              void* d_out, int out_size, void* d_ws, size_t ws_size,
                              hipStream_t stream) {
  const float* x  = (const float*)d_in[0];
  const float* W  = (const float*)d_in[1];   // (D, O)
  const float* b  = (const float*)d_in[2];   // (O,)
  const float* lA = (const float*)d_in[3];   // (E, D, R)
  const float* lB = (const float*)d_in[4];   // (E, R, O)
  const float* gw = (const float*)d_in[5];   // (E+1, D)
  // d_in[6] = bvv, unused by the reference
  float* out = (float*)d_out;

  char* ws = (char*)d_ws;
  __hip_bfloat16* BT    = (__hip_bfloat16*)(ws + BT_OFF);
  __hip_bfloat16* Ap    = (__hip_bfloat16*)(ws + AP_OFF);
  __hip_bfloat16* AT    = (__hip_bfloat16*)(ws + AT_OFF);
  float*          gates = (float*)(ws + G_OFF);

  // B'^T rows: [o][0:4096] = W^T, [o][4096+e*16+r] = lora_B[e][r][o]
  transpose_cast_kernel<<<dim3(64, 64), 256, 0, stream>>>(W, BT, Ocfg, KD, 0);
  transpose_cast_kernel<<<dim3(2, 64), 256, 0, stream>>>(lB, BT, Ocfg, KD, Dcfg);
  loraA_transpose_kernel<<<dim3(16, 8), 256, 0, stream>>>(lA, AT);
  gates_scale_kernel<<<dim3(Ncfg), 256, 0, stream>>>(x, gw, gates, Ap);
  lora_t_kernel<<<dim3(Ncfg / 16), 256, 0, stream>>>(x, AT, gates, Ap);
  gemm_kernel<<<dim3(Ocfg / 128, Ncfg / 128), 256, 0, stream>>>(Ap, BT, gates, b, out);
}